// Round 6
// baseline (267.871 us; speedup 1.0000x reference)
//
#include <hip/hip_runtime.h>
#include <hip/hip_bf16.h>

typedef __attribute__((ext_vector_type(8))) short short8;
typedef __attribute__((ext_vector_type(4))) float f32x4;
typedef unsigned short ushort_t;
typedef unsigned int uint_t;

#define D_MODEL 512
#define D_ATTN  64
#define LROW 1032   // padded bias row pitch (ushorts): breaks pow2 bank strides

__device__ __forceinline__ ushort_t f2bf(float f) {
    uint_t u = __float_as_uint(f);
    u += 0x7FFFu + ((u >> 16) & 1u);
    return (ushort_t)(u >> 16);
}
__device__ __forceinline__ float bf2f(ushort_t h) {
    return __uint_as_float((uint_t)h << 16);
}

// DMA 16B/lane: LDS dst = base + lane*16 (wave-uniform base), global src per-lane.
#define GLOAD16(g, s) __builtin_amdgcn_global_load_lds(                         \
    (const __attribute__((address_space(1))) unsigned int*)(g),                 \
    (__attribute__((address_space(3))) unsigned int*)(s), 16, 0, 0)

// ---------------- Kernel 1: QKV, 8 rows/wave (halved W re-reads) ----------------
__global__ __launch_bounds__(256)
void qkv_all(const float* __restrict__ x,
             const float* __restrict__ Wq, const float* __restrict__ bq,
             const float* __restrict__ Wk, const float* __restrict__ bk,
             const float* __restrict__ Wv, const float* __restrict__ bv,
             ushort_t* __restrict__ Q, ushort_t* __restrict__ K,
             ushort_t* __restrict__ Vt)
{
    const int l = threadIdx.x & 63, w = threadIdx.x >> 6;
    const size_t bn0 = (size_t)blockIdx.x << 5;   // 32 rows per block
    const int r0 = w << 3;                        // 8 rows per wave
    const float* xb = x + (bn0 + r0) * D_MODEL;
    { uintptr_t u = (uintptr_t)xb; asm volatile("" : "+v"(u)); xb = (const float*)u; }

    float aq[8], ak[8], av[8];
#pragma unroll
    for (int r = 0; r < 8; ++r) { aq[r] = 0.f; ak[r] = 0.f; av[r] = 0.f; }

    for (int k = 0; k < D_MODEL; k += 4) {
        float4 xr[8];
#pragma unroll
        for (int r = 0; r < 8; ++r) xr[r] = *(const float4*)(xb + r * D_MODEL + k);
        float wqv[4], wkv[4], wvv[4];
#pragma unroll
        for (int kk = 0; kk < 4; ++kk) {
            wqv[kk] = Wq[(k + kk) * D_ATTN + l];
            wkv[kk] = Wk[(k + kk) * D_ATTN + l];
            wvv[kk] = Wv[(k + kk) * D_ATTN + l];
        }
#pragma unroll
        for (int r = 0; r < 8; ++r) {
            const float xv[4] = {xr[r].x, xr[r].y, xr[r].z, xr[r].w};
#pragma unroll
            for (int kk = 0; kk < 4; ++kk) {
                aq[r] = fmaf(xv[kk], wqv[kk], aq[r]);
                ak[r] = fmaf(xv[kk], wkv[kk], ak[r]);
                av[r] = fmaf(xv[kk], wvv[kk], av[r]);
            }
        }
    }
    const float bqv = bq[l], bkv = bk[l], bvv = bv[l];
#pragma unroll
    for (int r = 0; r < 8; ++r) {
        Q[(bn0 + r0 + r) * D_ATTN + l] = f2bf((aq[r] + bqv) * 0.125f); // fold 1/sqrt(64)
        K[(bn0 + r0 + r) * D_ATTN + l] = f2bf(ak[r] + bkv);
    }
    const int b = (int)(bn0 >> 10), n0loc = (int)(bn0 & 1023);
    uint_t pk[4];
#pragma unroll
    for (int r = 0; r < 8; r += 2)
        pk[r >> 1] = (uint_t)f2bf(av[r] + bvv) | ((uint_t)f2bf(av[r + 1] + bvv) << 16);
    *(uint4*)(Vt + ((size_t)(b * 64 + l) << 10) + n0loc + r0) =
        make_uint4(pk[0], pk[1], pk[2], pk[3]);
}

// ---------------- Kernel 2: DMA-streamed bias + fused attention ----------------
// 512 blocks x 256 thr (4 waves). LDS ~56.8KB -> 2 blocks/CU.
// Phase A: 8KB chunks, 3-buffer ring, depth-2 global_load_lds prefetch,
// counted vmcnt(4) + raw barriers (m201 pattern) -> 32KB/CU reads in flight.
__global__ __launch_bounds__(256)
void topo_attn_f(const float* __restrict__ top, const float* __restrict__ Wt,
                 const ushort_t* __restrict__ Q, const ushort_t* __restrict__ K,
                 const ushort_t* __restrict__ Vt, float* __restrict__ out)
{
    __shared__ __align__(16) float stage[3 * 2048];   // 3 x 8KB ring
    __shared__ __align__(16) ushort_t sm[16 * LROW];  // bias bf16 -> later P bf16
    __shared__ float redm[64], reds[64];              // [q][wave] partials
    const int tid = threadIdx.x;
    const int l = tid & 63, w = tid >> 6;
    const int b   = blockIdx.x >> 6;
    const int bn0 = blockIdx.x << 4;                  // b*1024 + n0

    // ---- Phase A: bias[r][m] = top[bn0+r][m][:] . Wt  (537MB DMA stream) ----
    {
        const float* __restrict__ topb = top + ((size_t)bn0 << 14);
        const float4 wq = *(const float4*)(Wt + ((l & 3) << 2));  // my Wt quarter
        const int loff = (w << 9) + (l << 2);   // wave slab (512 f) + lane (4 f)

        // prologue: chunks 0,1
        {
            const float* s0 = topb + loff;
            GLOAD16(s0,       stage + (w << 9));
            GLOAD16(s0 + 256, stage + (w << 9) + 256);
            const float* s1 = topb + 2048 + loff;
            GLOAD16(s1,       stage + 2048 + (w << 9));
            GLOAD16(s1 + 256, stage + 2048 + (w << 9) + 256);
        }
        for (int c = 0; c < 128; ++c) {
            // issue chunk c+2 (tail: re-issue 127 -> identical bytes, benign;
            // keeps exactly 6 loads outstanding so vmcnt(4) retires chunk c's 2)
            int cc = (c + 2 > 127) ? 127 : (c + 2);
            {
                const float* s2 = topb + ((size_t)cc << 11) + loff;
                float* d2 = stage + (cc % 3) * 2048 + (w << 9);
                GLOAD16(s2,       d2);
                GLOAD16(s2 + 256, d2 + 256);
            }
            asm volatile("s_waitcnt vmcnt(4)" ::: "memory");
            __builtin_amdgcn_s_barrier();
            __builtin_amdgcn_sched_barrier(0);

            const float* sb = stage + (c % 3) * 2048;
            f32x4 u0 = *(const f32x4*)(sb + (((w << 7) + l) << 2));
            f32x4 u1 = *(const f32x4*)(sb + (((w << 7) + 64 + l) << 2));
            float p0 = u0[0] * wq.x; p0 = fmaf(u0[1], wq.y, p0);
            p0 = fmaf(u0[2], wq.z, p0); p0 = fmaf(u0[3], wq.w, p0);
            float p1 = u1[0] * wq.x; p1 = fmaf(u1[1], wq.y, p1);
            p1 = fmaf(u1[2], wq.z, p1); p1 = fmaf(u1[3], wq.w, p1);
            p0 += __shfl_xor(p0, 1); p0 += __shfl_xor(p0, 2);
            p1 += __shfl_xor(p1, 1); p1 += __shfl_xor(p1, 2);
            int r  = c >> 3;
            int mb = ((c & 7) << 7) + (w << 5) + (l >> 2);
            if ((l & 3) == 0) sm[r * LROW + mb]      = f2bf(p0);
            if ((l & 3) == 1) sm[r * LROW + mb + 16] = f2bf(p1);
            __builtin_amdgcn_s_barrier();
        }
        // bt dropped: softmax shift-invariant
    }
    __syncthreads();

    // ---- Phase B: swapped MFMA logits = K Q^T (+bias), registers ----
    const int lq = l & 15, lg4 = l >> 4;
    f32x4 lgt[16];
    {
        const short8 qb0 = *(const short8*)(Q + ((size_t)(bn0 + lq)) * 64 + 8 * lg4);
        const short8 qb1 = *(const short8*)(Q + ((size_t)(bn0 + lq)) * 64 + 32 + 8 * lg4);
        const ushort_t* __restrict__ Kb = K + ((size_t)b << 16);
#pragma unroll 4
        for (int t = 0; t < 16; ++t) {
            int m0 = (w << 8) + (t << 4);
            short8 kb0 = *(const short8*)(Kb + (size_t)(m0 + lq) * 64 + 8 * lg4);
            short8 kb1 = *(const short8*)(Kb + (size_t)(m0 + lq) * 64 + 32 + 8 * lg4);
            f32x4 acc = {0.f, 0.f, 0.f, 0.f};
            acc = __builtin_amdgcn_mfma_f32_16x16x32_bf16(kb0, qb0, acc, 0, 0, 0);
            acc = __builtin_amdgcn_mfma_f32_16x16x32_bf16(kb1, qb1, acc, 0, 0, 0);
            // D: col=lane&15 = query q, row=4*lg4+j = m-sub. Add bias[q][m]:
#pragma unroll
            for (int j = 0; j < 4; ++j)
                acc[j] += bf2f(sm[lq * LROW + m0 + 4 * lg4 + j]);
            lgt[t] = acc;
        }
    }

    // ---- Phase C: register softmax over this lane's query row (q = lq) ----
    {
        float mx = lgt[0][0];
#pragma unroll
        for (int t = 0; t < 16; ++t)
#pragma unroll
            for (int j = 0; j < 4; ++j) mx = fmaxf(mx, lgt[t][j]);
        mx = fmaxf(mx, __shfl_xor(mx, 16));
        mx = fmaxf(mx, __shfl_xor(mx, 32));
        if (l < 16) redm[l * 4 + w] = mx;
        __syncthreads();
        float gmx = fmaxf(fmaxf(redm[lq * 4 + 0], redm[lq * 4 + 1]),
                          fmaxf(redm[lq * 4 + 2], redm[lq * 4 + 3]));
        float s = 0.f;
#pragma unroll
        for (int t = 0; t < 16; ++t)
#pragma unroll
            for (int j = 0; j < 4; ++j) {
                float e = __expf(lgt[t][j] - gmx);
                lgt[t][j] = e; s += e;
            }
        s += __shfl_xor(s, 16);
        s += __shfl_xor(s, 32);
        if (l < 16) reds[l * 4 + w] = s;
        __syncthreads();   // also: all waves done reading bias from sm
        float inv = 1.0f / (reds[lq * 4 + 0] + reds[lq * 4 + 1]
                          + reds[lq * 4 + 2] + reds[lq * 4 + 3]);
        // write P bf16 into sm (overwrites bias): P[q][m]
#pragma unroll
        for (int t = 0; t < 16; ++t) {
            int mbase = (w << 8) + (t << 4) + 4 * lg4;
            uint_t w01 = (uint_t)f2bf(lgt[t][0] * inv) | ((uint_t)f2bf(lgt[t][1] * inv) << 16);
            uint_t w23 = (uint_t)f2bf(lgt[t][2] * inv) | ((uint_t)f2bf(lgt[t][3] * inv) << 16);
            *(uint_t*)(sm + lq * LROW + mbase)     = w01;
            *(uint_t*)(sm + lq * LROW + mbase + 2) = w23;
        }
    }
    __syncthreads();

    // ---- Phase D: out = P V ; wave w owns d-range [w*16, w*16+16) ----
    {
        f32x4 oe = {0,0,0,0}, oo = {0,0,0,0};
        const ushort_t* __restrict__ Vb = Vt + ((size_t)b << 16)
                                        + ((size_t)((w << 4) + lq) << 10);
        const ushort_t* __restrict__ pb = sm + lq * LROW + 8 * lg4;
#pragma unroll 4
        for (int kk = 0; kk < 32; kk += 2) {
            short8 pa0 = *(const short8*)(pb + (kk << 5));
            short8 vb0 = *(const short8*)(Vb + (kk << 5) + 8 * lg4);
            oe = __builtin_amdgcn_mfma_f32_16x16x32_bf16(pa0, vb0, oe, 0, 0, 0);
            short8 pa1 = *(const short8*)(pb + (kk << 5) + 32);
            short8 vb1 = *(const short8*)(Vb + (kk << 5) + 32 + 8 * lg4);
            oo = __builtin_amdgcn_mfma_f32_16x16x32_bf16(pa1, vb1, oo, 0, 0, 0);
        }
        // D: col=lane&15 = d-sub, row=4*lg4+j = query
#pragma unroll
        for (int j = 0; j < 4; ++j)
            out[((size_t)(bn0 + 4 * lg4 + j) << 6) + (w << 4) + lq] = oe[j] + oo[j];
    }
}

extern "C" void kernel_launch(void* const* d_in, const int* in_sizes, int n_in,
                              void* d_out, int out_size, void* d_ws, size_t ws_size,
                              hipStream_t stream) {
    const float* x   = (const float*)d_in[0];
    const float* top = (const float*)d_in[1];
    const float* Wq  = (const float*)d_in[2];
    const float* bq  = (const float*)d_in[3];
    const float* Wk  = (const float*)d_in[4];
    const float* bk  = (const float*)d_in[5];
    const float* Wv  = (const float*)d_in[6];
    const float* bv  = (const float*)d_in[7];
    const float* Wt  = (const float*)d_in[8];
    // d_in[9] = bt: softmax shift-invariant, dropped.
    float* out = (float*)d_out;

    ushort_t* Q  = (ushort_t*)d_ws;          // [8][1024][64] bf16 (pre-scaled 1/8)
    ushort_t* K  = Q + 8 * 1024 * 64;        // [8][1024][64] bf16
    ushort_t* Vt = K + 8 * 1024 * 64;        // [8][64][1024] bf16 (transposed)

    qkv_all<<<256, 256, 0, stream>>>(x, Wq, bq, Wk, bk, Wv, bv, Q, K, Vt);
    topo_attn_f<<<512, 256, 0, stream>>>(top, Wt, Q, K, Vt, out);
}

// Round 7
// 161.102 us; speedup vs baseline: 1.6627x; 1.6627x over previous
//
#include <hip/hip_runtime.h>
#include <hip/hip_bf16.h>

typedef __attribute__((ext_vector_type(8))) short short8;
typedef __attribute__((ext_vector_type(4))) float f32x4;
typedef unsigned short ushort_t;
typedef unsigned int uint_t;

#define D_MODEL 512
#define D_ATTN  64

__device__ __forceinline__ ushort_t f2bf(float f) {
    // round-to-nearest-even bf16 (finite inputs)
    uint_t u = __float_as_uint(f);
    u += 0x7FFFu + ((u >> 16) & 1u);
    return (ushort_t)(u >> 16);
}
__device__ __forceinline__ f32x4 ntload4(const f32x4* p) {
    return __builtin_nontemporal_load(p);   // top is read exactly once: stream hint
}

// ---------------- Kernel 1: QKV, all components per wave (R4-exact) ----------------
__global__ __launch_bounds__(256)
void qkv_all(const float* __restrict__ x,
             const float* __restrict__ Wq, const float* __restrict__ bq,
             const float* __restrict__ Wk, const float* __restrict__ bk,
             const float* __restrict__ Wv, const float* __restrict__ bv,
             ushort_t* __restrict__ Q, ushort_t* __restrict__ K,
             ushort_t* __restrict__ Vt)
{
    const int l = threadIdx.x & 63, w = threadIdx.x >> 6;
    const size_t bn0 = (size_t)blockIdx.x << 4;
    const int r0 = w << 2;
    const float* xb = x + (bn0 + r0) * D_MODEL;
    { uintptr_t u = (uintptr_t)xb; asm volatile("" : "+v"(u)); xb = (const float*)u; }

    float aq[4] = {0,0,0,0}, ak[4] = {0,0,0,0}, av[4] = {0,0,0,0};
#pragma unroll 2
    for (int k = 0; k < D_MODEL; k += 4) {
        float4 xr[4];
#pragma unroll
        for (int r = 0; r < 4; ++r) xr[r] = *(const float4*)(xb + r * D_MODEL + k);
        float wqv[4], wkv[4], wvv[4];
#pragma unroll
        for (int kk = 0; kk < 4; ++kk) {
            wqv[kk] = Wq[(k + kk) * D_ATTN + l];
            wkv[kk] = Wk[(k + kk) * D_ATTN + l];
            wvv[kk] = Wv[(k + kk) * D_ATTN + l];
        }
#pragma unroll
        for (int r = 0; r < 4; ++r) {
            const float xv[4] = {xr[r].x, xr[r].y, xr[r].z, xr[r].w};
#pragma unroll
            for (int kk = 0; kk < 4; ++kk) {
                aq[r] = fmaf(xv[kk], wqv[kk], aq[r]);
                ak[r] = fmaf(xv[kk], wkv[kk], ak[r]);
                av[r] = fmaf(xv[kk], wvv[kk], av[r]);
            }
        }
    }
    const float bqv = bq[l], bkv = bk[l], bvv = bv[l];
#pragma unroll
    for (int r = 0; r < 4; ++r) {
        Q[(bn0 + r0 + r) * D_ATTN + l] = f2bf((aq[r] + bqv) * 0.125f); // fold 1/sqrt(64)
        K[(bn0 + r0 + r) * D_ATTN + l] = f2bf(ak[r] + bkv);
    }
    const int b = (int)(bn0 >> 10), n0loc = (int)(bn0 & 1023);
    uint2 pv;
    pv.x = (uint_t)f2bf(av[0] + bvv) | ((uint_t)f2bf(av[1] + bvv) << 16);
    pv.y = (uint_t)f2bf(av[2] + bvv) | ((uint_t)f2bf(av[3] + bvv) << 16);
    *(uint2*)(Vt + ((size_t)(b * 64 + l) << 10) + n0loc + r0) = pv;
}

// ---------------- Kernel 2: fused stream + attention (R4 + 16-deep batching) ----------------
// 512 blocks x 256 thr, 64KB LDS, 2 blocks/CU. Phase A: 16 independent NT
// f32x4 loads in flight per wave (16KB/wave, 128KB/CU), zero barriers.
__global__ __launch_bounds__(256)
void topo_attn_f(const float* __restrict__ top, const float* __restrict__ Wt,
                 const ushort_t* __restrict__ Q, const ushort_t* __restrict__ K,
                 const ushort_t* __restrict__ Vt, float* __restrict__ out)
{
    __shared__ float lds[16384];
    const int tid = threadIdx.x;
    const int l = tid & 63, wv = tid >> 6;
    const int b   = blockIdx.x >> 6;
    const int bn0 = blockIdx.x << 4;   // b*1024 + n0

    // ---- Phase A: bias[r][m] = top[bn0+r][m][:] . Wt  (537MB stream) ----
    {
        // wave slab = rows 4wv..4wv+3, contiguous 256KB, flat j = 0..255 (1KB/j)
        const f32x4* __restrict__ slab =
            (const f32x4*)top + ((size_t)bn0 << 12) + ((size_t)wv << 14) + l;
        const float4 wq = *(const float4*)(Wt + ((l & 3) << 2));  // my Wt quarter
        const int mq = l >> 2;
        const bool sel0 = (l & 3) == 0;
#pragma unroll 1
        for (int bi = 0; bi < 16; ++bi) {
            f32x4 ld[16];
#pragma unroll
            for (int u = 0; u < 16; ++u)
                ld[u] = ntload4(slab + (((bi << 4) + u) << 6));
#pragma unroll
            for (int u = 0; u < 16; ++u) {
                int j = (bi << 4) + u;
                float p = ld[u][0] * wq.x;
                p = fmaf(ld[u][1], wq.y, p);
                p = fmaf(ld[u][2], wq.z, p);
                p = fmaf(ld[u][3], wq.w, p);
                p += __shfl_xor(p, 1);     // fold quarters across 4-lane group
                p += __shfl_xor(p, 2);
                int m_slab = (j << 4) + mq;            // 0..4095 within slab
                int rloc = (wv << 2) + (m_slab >> 10); // local query row 0..15
                int m = m_slab & 1023;
                if (sel0) lds[rloc * 1024 + m] = p;    // 16 lanes -> 16 banks
            }
        }
        // bt dropped: softmax shift-invariant
    }
    __syncthreads();

    // ---- Phase B: logits += (Q/8) K^T via MFMA ----
    const int lr = l & 15, lg = l >> 4;
    const short8 a0 = *(const short8*)(Q + ((size_t)(bn0 + lr)) * 64 + 8 * lg);
    const short8 a1 = *(const short8*)(Q + ((size_t)(bn0 + lr)) * 64 + 32 + 8 * lg);
    const ushort_t* __restrict__ Kb = K + ((size_t)b << 16);
#pragma unroll 4
    for (int t16 = 0; t16 < 16; ++t16) {
        int m0 = (wv << 8) + (t16 << 4);
        short8 kb0 = *(const short8*)(Kb + (size_t)(m0 + lr) * 64 + 8 * lg);
        short8 kb1 = *(const short8*)(Kb + (size_t)(m0 + lr) * 64 + 32 + 8 * lg);
        f32x4 acc = {0.f, 0.f, 0.f, 0.f};
        acc = __builtin_amdgcn_mfma_f32_16x16x32_bf16(a0, kb0, acc, 0, 0, 0);
        acc = __builtin_amdgcn_mfma_f32_16x16x32_bf16(a1, kb1, acc, 0, 0, 0);
#pragma unroll
        for (int j = 0; j < 4; ++j)
            lds[(4 * lg + j) * 1024 + m0 + lr] += acc[j];  // C/D: col=lane&15, row=4*(l>>4)+j
    }
    __syncthreads();

    // ---- Phase C: row softmax; write P (bf16) aliased over logits[0:32KB) ----
    {
        const int r = tid >> 4, sseg = tid & 15;
        float4 v4[16];
        const float4* rowp = (const float4*)(lds + r * 1024 + sseg * 64);
#pragma unroll
        for (int i = 0; i < 16; ++i) v4[i] = rowp[i];
        __syncthreads();   // everyone finished reading logits before alias overwrite
        float mx = v4[0].x;
#pragma unroll
        for (int i = 0; i < 16; ++i)
            mx = fmaxf(mx, fmaxf(fmaxf(v4[i].x, v4[i].y), fmaxf(v4[i].z, v4[i].w)));
#pragma unroll
        for (int off = 8; off >= 1; off >>= 1) mx = fmaxf(mx, __shfl_xor(mx, off));
        float sum = 0.f;
#pragma unroll
        for (int i = 0; i < 16; ++i) {
            v4[i].x = __expf(v4[i].x - mx); sum += v4[i].x;
            v4[i].y = __expf(v4[i].y - mx); sum += v4[i].y;
            v4[i].z = __expf(v4[i].z - mx); sum += v4[i].z;
            v4[i].w = __expf(v4[i].w - mx); sum += v4[i].w;
        }
#pragma unroll
        for (int off = 8; off >= 1; off >>= 1) sum += __shfl_xor(sum, off);
        float inv = 1.0f / sum;
        ushort_t* pb = ((ushort_t*)lds) + r * 1024 + sseg * 64;
#pragma unroll
        for (int i = 0; i < 8; ++i) {
            uint_t w0 = (uint_t)f2bf(v4[2*i].x * inv)   | ((uint_t)f2bf(v4[2*i].y * inv)   << 16);
            uint_t w1 = (uint_t)f2bf(v4[2*i].z * inv)   | ((uint_t)f2bf(v4[2*i].w * inv)   << 16);
            uint_t w2 = (uint_t)f2bf(v4[2*i+1].x * inv) | ((uint_t)f2bf(v4[2*i+1].y * inv) << 16);
            uint_t w3 = (uint_t)f2bf(v4[2*i+1].z * inv) | ((uint_t)f2bf(v4[2*i+1].w * inv) << 16);
            ((uint4*)pb)[i] = make_uint4(w0, w1, w2, w3);
        }
    }
    __syncthreads();

    // ---- Phase D: out = P V  (V transposed -> contiguous B-frag loads) ----
    {
        f32x4 o[4] = {{0,0,0,0},{0,0,0,0},{0,0,0,0},{0,0,0,0}};
        const ushort_t* __restrict__ pb = ((const ushort_t*)lds) + lr * 1024;
        const ushort_t* __restrict__ Vb = Vt + ((size_t)b << 16);
#pragma unroll 2
        for (int c = 0; c < 8; ++c) {
            int m0 = (wv << 8) + (c << 5) + 8 * lg;
            short8 pa = *(const short8*)(pb + m0);
#pragma unroll
            for (int dt = 0; dt < 4; ++dt) {
                short8 vb = *(const short8*)(Vb + (size_t)(dt * 16 + lr) * 1024 + m0);
                o[dt] = __builtin_amdgcn_mfma_f32_16x16x32_bf16(pa, vb, o[dt], 0, 0, 0);
            }
        }
        float* lo = lds + 8192 + (wv << 10);   // scratch aliases consumed logits
#pragma unroll
        for (int dt = 0; dt < 4; ++dt)
#pragma unroll
            for (int j = 0; j < 4; ++j)
                lo[(4 * lg + j) * 64 + dt * 16 + lr] = o[dt][j];
    }
    __syncthreads();

    // ---- cross-wave reduce + coalesced store ----
#pragma unroll
    for (int i = 0; i < 4; ++i) {
        int idx = (i << 8) + tid;   // r*64 + d
        float s2 = lds[8192 + idx] + lds[8192 + 1024 + idx]
                 + lds[8192 + 2048 + idx] + lds[8192 + 3072 + idx];
        out[((size_t)bn0 << 6) + idx] = s2;
    }
}

extern "C" void kernel_launch(void* const* d_in, const int* in_sizes, int n_in,
                              void* d_out, int out_size, void* d_ws, size_t ws_size,
                              hipStream_t stream) {
    const float* x   = (const float*)d_in[0];
    const float* top = (const float*)d_in[1];
    const float* Wq  = (const float*)d_in[2];
    const float* bq  = (const float*)d_in[3];
    const float* Wk  = (const float*)d_in[4];
    const float* bk  = (const float*)d_in[5];
    const float* Wv  = (const float*)d_in[6];
    const float* bv  = (const float*)d_in[7];
    const float* Wt  = (const float*)d_in[8];
    // d_in[9] = bt: constant added to every logit -> softmax-invariant, dropped.
    float* out = (float*)d_out;

    ushort_t* Q  = (ushort_t*)d_ws;          // [8][1024][64] bf16 (pre-scaled 1/8)
    ushort_t* K  = Q + 8 * 1024 * 64;        // [8][1024][64] bf16
    ushort_t* Vt = K + 8 * 1024 * 64;        // [8][64][1024] bf16 (transposed)

    qkv_all<<<512, 256, 0, stream>>>(x, Wq, bq, Wk, bk, Wv, bv, Q, K, Vt);
    topo_attn_f<<<512, 256, 0, stream>>>(top, Wt, Q, K, Vt, out);
}